// Round 4
// baseline (1533.441 us; speedup 1.0000x reference)
//
#include <hip/hip_runtime.h>
#include <math.h>

#define HH 128
#define HP 64   // u32 pairs per 128-feature row

typedef __attribute__((ext_vector_type(8))) short short8;
typedef __attribute__((ext_vector_type(4))) float float4v;
typedef __attribute__((ext_vector_type(4))) unsigned uint4v;

// ---------- helpers ----------
__device__ __forceinline__ float blo(unsigned w){ return __uint_as_float(w << 16); }
__device__ __forceinline__ float bhi(unsigned w){ return __uint_as_float(w & 0xffff0000u); }
__device__ __forceinline__ unsigned short f2b(float x){
  unsigned u = __float_as_uint(x);
  u += 0x7fffu + ((u >> 16) & 1u);           // RNE to bf16
  return (unsigned short)(u >> 16);
}
__device__ __forceinline__ unsigned pack2(float a, float b){
  return (unsigned)f2b(a) | ((unsigned)f2b(b) << 16);
}
__device__ __forceinline__ float silu_f(float x){ return x / (1.f + __expf(-x)); }

// ---------- sort-by-dst kernels ----------
__global__ void hist_kernel(const int* __restrict__ dst, unsigned* __restrict__ hist, int E){
  int i = blockIdx.x * blockDim.x + threadIdx.x;
  int st = gridDim.x * blockDim.x;
  for (; i < E; i += st) atomicAdd(&hist[dst[i]], 1u);
}

__global__ void scan_block_kernel(const unsigned* __restrict__ hist,
                                  unsigned* __restrict__ offs,
                                  unsigned* __restrict__ bsums, int N){
  __shared__ unsigned s[256];
  int t = threadIdx.x, g = blockIdx.x * 256 + t;
  unsigned v = (g < N) ? hist[g] : 0u;
  s[t] = v; __syncthreads();
  for (int o = 1; o < 256; o <<= 1) {
    unsigned a = (t >= o) ? s[t - o] : 0u; __syncthreads();
    s[t] += a; __syncthreads();
  }
  unsigned incl = s[t];
  if (g < N) offs[g] = incl - v;
  if (t == 255) bsums[blockIdx.x] = incl;
}

__global__ void scan_top_kernel(unsigned* __restrict__ bsums, int NB){
  __shared__ unsigned s[256];
  int t = threadIdx.x;
  unsigned v = (t < NB) ? bsums[t] : 0u;
  s[t] = v; __syncthreads();
  for (int o = 1; o < 256; o <<= 1) {
    unsigned a = (t >= o) ? s[t - o] : 0u; __syncthreads();
    s[t] += a; __syncthreads();
  }
  unsigned incl = s[t];
  if (t < NB) bsums[t] = incl - v;           // exclusive
}

__global__ void scan_add_kernel(unsigned* __restrict__ offs,
                                const unsigned* __restrict__ bsums, int N){
  int g = blockIdx.x * 256 + threadIdx.x;
  if (g < N) offs[g] += bsums[blockIdx.x];
}

__global__ void scatter_kernel(const int* __restrict__ dst, unsigned* __restrict__ offs,
                               int* __restrict__ perm, int E){
  int i = blockIdx.x * blockDim.x + threadIdx.x;
  int st = gridDim.x * blockDim.x;
  for (; i < E; i += st) {
    unsigned pos = atomicAdd(&offs[dst[i]], 1u);
    perm[pos] = i;
  }
}

// ---------- per-node precompute: A = h@W[0:128] + bias, B = h@W[128:256] ----------
__global__ __launch_bounds__(256) void precompute_kernel(
    const float* __restrict__ h, const float* __restrict__ W,
    const float* __restrict__ bias,
    unsigned* __restrict__ Aout, unsigned* __restrict__ Bout, int N)
{
  __shared__ unsigned Wl[256 * HP];           // 64 KB
  int t = threadIdx.x;
  const float2* W2 = (const float2*)W;
  for (int i = t; i < 256 * HP; i += 256) {
    float2 w = W2[i];
    Wl[i] = pack2(w.x, w.y);
  }
  __syncthreads();

  int wid = blockIdx.x * 4 + (t >> 6);
  int nw  = gridDim.x * 4;
  int jp  = t & 63;
  for (int n = wid; n < N; n += nw) {
    const float4* hn = (const float4*)(h + (size_t)n * HH);
    float a0 = 0.f, a1 = 0.f, b0 = 0.f, b1 = 0.f;
    #pragma unroll 8
    for (int k4 = 0; k4 < 32; ++k4) {
      float4 hv = hn[k4];
      float xs[4] = {hv.x, hv.y, hv.z, hv.w};
      #pragma unroll
      for (int u = 0; u < 4; ++u) {
        int k = 4 * k4 + u;
        unsigned wa = Wl[k * HP + jp];
        unsigned wb = Wl[(128 + k) * HP + jp];
        a0 += xs[u] * blo(wa); a1 += xs[u] * bhi(wa);
        b0 += xs[u] * blo(wb); b1 += xs[u] * bhi(wb);
      }
    }
    a0 += bias[2 * jp]; a1 += bias[2 * jp + 1];
    Aout[(size_t)n * HP + jp] = pack2(a0, a1);
    Bout[(size_t)n * HP + jp] = pack2(b0, b1);
  }
}

// ---------- MFMA edge kernels, wave-private 16-edge tiles, NO inner barriers ----------
// Layer-1 tail done via operand-swapped MFMA (A=weights, B=tail feats, D edge-on-col);
// gathered partials added in C-layout; LDS round-trip to A-layout; layer-2 MFMA as before.
template<int MODE>
__global__ __launch_bounds__(512, 4) void edge_kernel(
    const unsigned* __restrict__ Apart, const unsigned* __restrict__ Bpart,
    const float* __restrict__ W1,       // (276,128); rows 256..275 = tail
    const float* __restrict__ W2, const float* __restrict__ b2,
    const float* __restrict__ Wv, const float* __restrict__ ba_p,
    const int* __restrict__ src, const int* __restrict__ dst,
    const int* __restrict__ perm,
    const float* __restrict__ coords, const float* __restrict__ afeat,
    float* __restrict__ out_agg, int E)
{
  __shared__ __align__(16) unsigned short W2Ts[128 * 136]; // 34.8 KB, n-major bf16
  __shared__ __align__(16) unsigned mhl[8][16 * 68];       // 34.8 KB wave-private

  const int t = threadIdx.x;
  const int lane = t & 63;
  const int w = t >> 6;                       // 0..7
  const int col = lane & 15;
  const int quad = lane >> 4;

  // stage W2 transposed as bf16 (once per block)
  for (int i = t; i < 128 * 128; i += 512) {
    int k = i >> 7, n = i & 127;
    W2Ts[n * 136 + k] = f2b(W2[i]);
  }

  // tail-weight A-fragments in registers: A[m=out16-block nt][k=8*quad+j]
  // k-permutation: k 0..15 -> a_k (W1 row 260+k); k 16..19 -> rad,|dx|,|dy|,|dz| (row 240+k); k>=20 -> 0
  unsigned WtA[8][4];
  #pragma unroll
  for (int nt = 0; nt < 8; ++nt) {
    #pragma unroll
    for (int jp = 0; jp < 4; ++jp) {
      int k0 = 8 * quad + 2 * jp, k1 = k0 + 1;
      int n = nt * 16 + col;
      float w0 = (k0 < 16) ? W1[(260 + k0) * 128 + n] : (k0 < 20 ? W1[(240 + k0) * 128 + n] : 0.f);
      float w1 = (k1 < 16) ? W1[(260 + k1) * 128 + n] : (k1 < 20 ? W1[(240 + k1) * 128 + n] : 0.f);
      WtA[nt][jp] = pack2(w0, w1);
    }
  }
  float b2reg[8], wvreg[8];
  #pragma unroll
  for (int nt = 0; nt < 8; ++nt) {
    int n = nt * 16 + col;
    b2reg[nt] = b2[n];
    wvreg[nt] = Wv[n];
  }
  const float bav = (MODE == 0) ? ba_p[0] : 0.f;
  __syncthreads();                            // W2Ts ready (only block-wide barrier)

  const int ntiles = (E + 15) >> 4;
  const int nwaves = gridDim.x * 8;
  for (int tile = blockIdx.x * 8 + w; tile += 0, tile < ntiles; tile += nwaves) {
    const int e0 = tile * 16;

    // ---- per-edge scalars in lanes 0..15, broadcast via shuffles ----
    int pe0 = 0, s0 = 0, d0 = 0;
    float dx0 = 0.f, dy0 = 0.f, dz0 = 0.f, rad0 = 0.f;
    if (lane < 16) {
      int eg = e0 + lane;
      bool v = eg < E;
      pe0 = v ? perm[eg] : 0;
      s0 = v ? src[pe0] : 0;
      d0 = v ? dst[pe0] : 0;
      dx0 = coords[s0*3+0] - coords[d0*3+0];
      dy0 = coords[s0*3+1] - coords[d0*3+1];
      dz0 = coords[s0*3+2] - coords[d0*3+2];
      rad0 = sqrtf(dx0*dx0 + dy0*dy0 + dz0*dz0);
    }
    const int pe = __shfl(pe0, col, 64);
    const int sA = __shfl(s0, col, 64);
    const int dB = __shfl(d0, col, 64);
    const float dvx = __shfl(dx0, col, 64);
    const float dvy = __shfl(dy0, col, 64);
    const float dvz = __shfl(dz0, col, 64);
    const float dvr = __shfl(rad0, col, 64);

    // ---- tail B-fragment: B[k=8*quad+j][n=edge col] ----
    unsigned tb0, tb1, tb2, tb3;
    if (quad < 2) {
      const float4* ap = (const float4*)(afeat + (size_t)pe * 16 + quad * 8);
      float4 a0 = ap[0], a1 = ap[1];
      tb0 = pack2(a0.x, a0.y); tb1 = pack2(a0.z, a0.w);
      tb2 = pack2(a1.x, a1.y); tb3 = pack2(a1.z, a1.w);
    } else if (quad == 2) {
      tb0 = pack2(dvr, fabsf(dvx)); tb1 = pack2(fabsf(dvy), fabsf(dvz));
      tb2 = 0u; tb3 = 0u;
    } else {
      tb0 = 0u; tb1 = 0u; tb2 = 0u; tb3 = 0u;
    }
    uint4v tbv = {tb0, tb1, tb2, tb3};
    short8 tailB = __builtin_bit_cast(short8, tbv);

    // ---- gathered layer-1 partials in C-layout positions ----
    const unsigned* Arow = Apart + (size_t)sA * HP;
    const unsigned* Brow = Bpart + (size_t)dB * HP;

    // ---- tail MFMAs + add partials + silu -> mhl (A-layout for layer 2) ----
    #pragma unroll
    for (int nt = 0; nt < 8; ++nt) {
      uint2 ga = *(const uint2*)(Arow + 8 * nt + 2 * quad);
      uint2 gb = *(const uint2*)(Brow + 8 * nt + 2 * quad);
      float4v zero = {0.f, 0.f, 0.f, 0.f};
      float4v l1 = __builtin_amdgcn_mfma_f32_16x16x32_bf16(
          __builtin_bit_cast(short8, *(const uint4v*)WtA[nt]), tailB, zero, 0, 0, 0);
      float v0 = silu_f(l1[0] + blo(ga.x) + blo(gb.x));
      float v1 = silu_f(l1[1] + bhi(ga.x) + bhi(gb.x));
      float v2 = silu_f(l1[2] + blo(ga.y) + blo(gb.y));
      float v3 = silu_f(l1[3] + bhi(ga.y) + bhi(gb.y));
      uint2 pk = make_uint2(pack2(v0, v1), pack2(v2, v3));
      *(uint2*)&mhl[w][col * 68 + 8 * nt + 2 * quad] = pk;
    }

    // ---- layer 2 via MFMA (wave covers 16 edges x 128 outputs) ----
    float4v acc[8] = {{0,0,0,0},{0,0,0,0},{0,0,0,0},{0,0,0,0},
                      {0,0,0,0},{0,0,0,0},{0,0,0,0},{0,0,0,0}};
    #pragma unroll
    for (int ks = 0; ks < 4; ++ks) {
      short8 af = __builtin_bit_cast(short8,
          *(const uint4v*)&mhl[w][col * 68 + ks * 16 + 4 * quad]);
      #pragma unroll
      for (int nt = 0; nt < 8; ++nt) {
        const unsigned short* bp = &W2Ts[(nt*16 + col)*136 + ks*32 + quad*8];
        short8 bf = __builtin_bit_cast(short8, *(const uint4v*)bp);
        acc[nt] = __builtin_amdgcn_mfma_f32_16x16x32_bf16(af, bf, acc[nt], 0, 0, 0);
      }
    }

    // ---- epilogue: bias+silu, head dot, 16-lane reduce, run-combined scatter ----
    float vv[8][4];
    float p[4] = {0.f, 0.f, 0.f, 0.f};
    #pragma unroll
    for (int nt = 0; nt < 8; ++nt)
      #pragma unroll
      for (int r = 0; r < 4; ++r) {
        float v = silu_f(acc[nt][r] + b2reg[nt]);
        vv[nt][r] = v;
        p[r] += v * wvreg[nt];
      }
    #pragma unroll
    for (int r = 0; r < 4; ++r) {
      #pragma unroll
      for (int off = 1; off < 16; off <<= 1) p[r] += __shfl_xor(p[r], off, 64);
    }
    int dq[4];
    #pragma unroll
    for (int r = 0; r < 4; ++r) dq[r] = __shfl(d0, quad * 4 + r, 64);

    if (MODE == 0) {
      float att[4];
      #pragma unroll
      for (int r = 0; r < 4; ++r) {
        int eg = e0 + quad * 4 + r;
        att[r] = (eg < E) ? 1.f / (1.f + __expf(-(p[r] + bav))) : 0.f;
      }
      #pragma unroll
      for (int nt = 0; nt < 8; ++nt) {
        int n = nt * 16 + col;
        float accm = att[0] * vv[nt][0];
        int dprev = dq[0];
        #pragma unroll
        for (int r = 1; r < 4; ++r) {
          float val = att[r] * vv[nt][r];
          if (dq[r] == dprev) accm += val;     // quad-uniform branch
          else {
            unsafeAtomicAdd(&out_agg[(size_t)dprev * HH + n], accm);
            dprev = dq[r]; accm = val;
          }
        }
        unsafeAtomicAdd(&out_agg[(size_t)dprev * HH + n], accm);
      }
    } else {
      float dxq[4], dyq[4], dzq[4], rq[4];
      #pragma unroll
      for (int r = 0; r < 4; ++r) {
        dxq[r] = __shfl(dx0, quad * 4 + r, 64);
        dyq[r] = __shfl(dy0, quad * 4 + r, 64);
        dzq[r] = __shfl(dz0, quad * 4 + r, 64);
        rq[r]  = __shfl(rad0, quad * 4 + r, 64);
      }
      if (col < 3) {
        float accm = 0.f;
        int dprev = dq[0];
        #pragma unroll
        for (int r = 0; r < 4; ++r) {
          int eg = e0 + quad * 4 + r;
          float fac = (eg < E) ? p[r] / (rq[r] + 1.f) : 0.f;
          float dcomp = (col == 0) ? dxq[r] : ((col == 1) ? dyq[r] : dzq[r]);
          float val = fac * dcomp;
          if (r > 0 && dq[r] != dprev) {
            unsafeAtomicAdd(&out_agg[(size_t)dprev * 3 + col], accm);
            dprev = dq[r]; accm = 0.f;
          }
          accm += val;
        }
        unsafeAtomicAdd(&out_agg[(size_t)dprev * 3 + col], accm);
      }
    }
    // no barrier: wave-private LDS + in-order DS ops make next tile safe
  }
}

// ---------- node MLP layer 1 ----------
__global__ __launch_bounds__(256) void node_l1_kernel(
    const float* __restrict__ h, const float* __restrict__ h_agg,
    const float* __restrict__ Wn1, const float* __restrict__ bn1,
    unsigned* __restrict__ g, int N)
{
  __shared__ unsigned Wl[256 * HP];
  int t = threadIdx.x;
  const float2* W2 = (const float2*)Wn1;
  for (int i = t; i < 256 * HP; i += 256) { float2 w = W2[i]; Wl[i] = pack2(w.x, w.y); }
  __syncthreads();

  int wid = blockIdx.x * 4 + (t >> 6);
  int nw  = gridDim.x * 4;
  int jp  = t & 63;
  for (int n = wid; n < N; n += nw) {
    float a0 = bn1[2*jp], a1 = bn1[2*jp + 1];
    const float4* hn = (const float4*)(h + (size_t)n * HH);
    const float4* gn = (const float4*)(h_agg + (size_t)n * HH);
    #pragma unroll 4
    for (int k4 = 0; k4 < 32; ++k4) {
      float4 hv = hn[k4];
      float xs[4] = {hv.x, hv.y, hv.z, hv.w};
      #pragma unroll
      for (int u = 0; u < 4; ++u) {
        unsigned w = Wl[(4*k4 + u) * HP + jp];
        a0 += xs[u] * blo(w); a1 += xs[u] * bhi(w);
      }
    }
    #pragma unroll 4
    for (int k4 = 0; k4 < 32; ++k4) {
      float4 hv = gn[k4];
      float xs[4] = {hv.x, hv.y, hv.z, hv.w};
      #pragma unroll
      for (int u = 0; u < 4; ++u) {
        unsigned w = Wl[(128 + 4*k4 + u) * HP + jp];
        a0 += xs[u] * blo(w); a1 += xs[u] * bhi(w);
      }
    }
    g[(size_t)n * HP + jp] = pack2(silu_f(a0), silu_f(a1));
  }
}

// ---------- node MLP layer 2 ----------
__global__ __launch_bounds__(256) void node_l2_kernel(
    const unsigned* __restrict__ g, const float* __restrict__ h,
    const float* __restrict__ Wn2, const float* __restrict__ bn2,
    float* __restrict__ hout, int N)
{
  __shared__ unsigned Wl[128 * HP];
  int t = threadIdx.x;
  const float2* W2 = (const float2*)Wn2;
  for (int i = t; i < 128 * HP; i += 256) { float2 w = W2[i]; Wl[i] = pack2(w.x, w.y); }
  __syncthreads();

  int wid = blockIdx.x * 4 + (t >> 6);
  int nw  = gridDim.x * 4;
  int jp  = t & 63;
  for (int n = wid; n < N; n += nw) {
    float a0 = bn2[2*jp], a1 = bn2[2*jp + 1];
    const uint2* gn = (const uint2*)(g + (size_t)n * HP);
    #pragma unroll 4
    for (int k2 = 0; k2 < 32; ++k2) {
      uint2 gp = gn[k2];
      float x0 = blo(gp.x), x1 = bhi(gp.x), x2 = blo(gp.y), x3 = bhi(gp.y);
      unsigned w0 = Wl[(4*k2    ) * HP + jp];
      unsigned w1 = Wl[(4*k2 + 1) * HP + jp];
      unsigned w2 = Wl[(4*k2 + 2) * HP + jp];
      unsigned w3 = Wl[(4*k2 + 3) * HP + jp];
      a0 += x0*blo(w0) + x1*blo(w1) + x2*blo(w2) + x3*blo(w3);
      a1 += x0*bhi(w0) + x1*bhi(w1) + x2*bhi(w2) + x3*bhi(w3);
    }
    float2 hv = ((const float2*)h)[(size_t)n * HP + jp];
    ((float2*)hout)[(size_t)n * HP + jp] = make_float2(hv.x + a0, hv.y + a1);
  }
}

// ---------- coords_out = coords + x_agg ----------
__global__ void coords_out_kernel(const float* __restrict__ coords,
                                  const float* __restrict__ x_agg,
                                  float* __restrict__ out, int n3)
{
  int i = blockIdx.x * blockDim.x + threadIdx.x;
  if (i < n3) out[i] = coords[i] + x_agg[i];
}

extern "C" void kernel_launch(void* const* d_in, const int* in_sizes, int n_in,
                              void* d_out, int out_size, void* d_ws, size_t ws_size,
                              hipStream_t stream)
{
  const float* h      = (const float*)d_in[0];
  const float* coords = (const float*)d_in[1];
  const float* afeat  = (const float*)d_in[2];
  const int*   src    = (const int*)d_in[3];
  const int*   dst    = (const int*)d_in[4];
  const float* We1 = (const float*)d_in[5];
  const float* be1 = (const float*)d_in[6];
  const float* We2 = (const float*)d_in[7];
  const float* be2 = (const float*)d_in[8];
  const float* Wa  = (const float*)d_in[9];
  const float* ba  = (const float*)d_in[10];
  const float* Wn1 = (const float*)d_in[11];
  const float* bn1 = (const float*)d_in[12];
  const float* Wn2 = (const float*)d_in[13];
  const float* bn2 = (const float*)d_in[14];
  const float* Wc1 = (const float*)d_in[15];
  const float* bc1 = (const float*)d_in[16];
  const float* Wc2 = (const float*)d_in[17];
  const float* bc2 = (const float*)d_in[18];
  const float* Wc3 = (const float*)d_in[19];

  const int E = in_sizes[3];
  const int N = in_sizes[0] / HH;

  unsigned* A1 = (unsigned*)d_ws;
  unsigned* B1 = A1 + (size_t)N * HP;
  unsigned* Ac = B1 + (size_t)N * HP;
  unsigned* Bc = Ac + (size_t)N * HP;
  float* h_agg = (float*)(Bc + (size_t)N * HP);
  float* x_agg = h_agg + (size_t)N * HH;
  int*   perm  = (int*)(x_agg + (size_t)N * 3);
  unsigned* histb = (unsigned*)(perm + E);
  unsigned* offs  = histb + N;
  unsigned* bsums = offs + N;
  unsigned* gbuf = A1;                        // reuse after edge kernels finish

  hipMemsetAsync(histb, 0, (size_t)N * sizeof(unsigned), stream);
  hipMemsetAsync(h_agg, 0, ((size_t)N * HH + (size_t)N * 3) * sizeof(float), stream);

  // counting sort of edges by dst
  hist_kernel<<<512, 256, 0, stream>>>(dst, histb, E);
  int NB = (N + 255) / 256;
  scan_block_kernel<<<NB, 256, 0, stream>>>(histb, offs, bsums, N);
  scan_top_kernel<<<1, 256, 0, stream>>>(bsums, NB);
  scan_add_kernel<<<NB, 256, 0, stream>>>(offs, bsums, N);
  scatter_kernel<<<512, 256, 0, stream>>>(dst, offs, perm, E);

  precompute_kernel<<<512, 256, 0, stream>>>(h, We1, be1, A1, B1, N);
  precompute_kernel<<<512, 256, 0, stream>>>(h, Wc1, bc1, Ac, Bc, N);

  edge_kernel<0><<<512, 512, 0, stream>>>(A1, B1, We1, We2, be2, Wa, ba,
                                          src, dst, perm, coords, afeat, h_agg, E);
  edge_kernel<1><<<512, 512, 0, stream>>>(Ac, Bc, Wc1, Wc2, bc2, Wc3, nullptr,
                                          src, dst, perm, coords, afeat, x_agg, E);

  node_l1_kernel<<<512, 256, 0, stream>>>(h, h_agg, Wn1, bn1, gbuf, N);
  node_l2_kernel<<<1024, 256, 0, stream>>>(gbuf, h, Wn2, bn2, (float*)d_out, N);
  coords_out_kernel<<<(N * 3 + 255) / 256, 256, 0, stream>>>(
      coords, x_agg, (float*)d_out + (size_t)N * HH, N * 3);
}

// Round 5
// 1395.990 us; speedup vs baseline: 1.0985x; 1.0985x over previous
//
#include <hip/hip_runtime.h>
#include <math.h>

#define HH 128
#define HP 64   // u32 pairs per 128-feature row

typedef __attribute__((ext_vector_type(8))) short short8;
typedef __attribute__((ext_vector_type(4))) float float4v;
typedef __attribute__((ext_vector_type(4))) unsigned uint4v;

// ---------- helpers ----------
__device__ __forceinline__ float blo(unsigned w){ return __uint_as_float(w << 16); }
__device__ __forceinline__ float bhi(unsigned w){ return __uint_as_float(w & 0xffff0000u); }
__device__ __forceinline__ unsigned short f2b(float x){
  unsigned u = __float_as_uint(x);
  u += 0x7fffu + ((u >> 16) & 1u);           // RNE to bf16
  return (unsigned short)(u >> 16);
}
__device__ __forceinline__ unsigned pack2(float a, float b){
  return (unsigned)f2b(a) | ((unsigned)f2b(b) << 16);
}
__device__ __forceinline__ float silu_f(float x){ return x / (1.f + __expf(-x)); }

// ---------- sort-by-dst kernels ----------
__global__ void hist_kernel(const int* __restrict__ dst, unsigned* __restrict__ hist, int E){
  int i = blockIdx.x * blockDim.x + threadIdx.x;
  int st = gridDim.x * blockDim.x;
  for (; i < E; i += st) atomicAdd(&hist[dst[i]], 1u);
}

__global__ void scan_block_kernel(const unsigned* __restrict__ hist,
                                  unsigned* __restrict__ offs,
                                  unsigned* __restrict__ bsums, int N){
  __shared__ unsigned s[256];
  int t = threadIdx.x, g = blockIdx.x * 256 + t;
  unsigned v = (g < N) ? hist[g] : 0u;
  s[t] = v; __syncthreads();
  for (int o = 1; o < 256; o <<= 1) {
    unsigned a = (t >= o) ? s[t - o] : 0u; __syncthreads();
    s[t] += a; __syncthreads();
  }
  unsigned incl = s[t];
  if (g < N) offs[g] = incl - v;
  if (t == 255) bsums[blockIdx.x] = incl;
}

__global__ void scan_top_kernel(unsigned* __restrict__ bsums, int NB){
  __shared__ unsigned s[256];
  int t = threadIdx.x;
  unsigned v = (t < NB) ? bsums[t] : 0u;
  s[t] = v; __syncthreads();
  for (int o = 1; o < 256; o <<= 1) {
    unsigned a = (t >= o) ? s[t - o] : 0u; __syncthreads();
    s[t] += a; __syncthreads();
  }
  unsigned incl = s[t];
  if (t < NB) bsums[t] = incl - v;           // exclusive
}

__global__ void scan_add_kernel(unsigned* __restrict__ offs,
                                const unsigned* __restrict__ bsums, int N){
  int g = blockIdx.x * 256 + threadIdx.x;
  if (g < N) offs[g] += bsums[blockIdx.x];
}

__global__ void scatter_kernel(const int* __restrict__ dst, unsigned* __restrict__ offs,
                               int* __restrict__ perm, int E){
  int i = blockIdx.x * blockDim.x + threadIdx.x;
  int st = gridDim.x * blockDim.x;
  for (; i < E; i += st) {
    unsigned pos = atomicAdd(&offs[dst[i]], 1u);
    perm[pos] = i;
  }
}

// ---------- per-node precompute: A = h@W[0:128] + bias, B = h@W[128:256] ----------
__global__ __launch_bounds__(256) void precompute_kernel(
    const float* __restrict__ h, const float* __restrict__ W,
    const float* __restrict__ bias,
    unsigned* __restrict__ Aout, unsigned* __restrict__ Bout, int N)
{
  __shared__ unsigned Wl[256 * HP];           // 64 KB
  int t = threadIdx.x;
  const float2* W2 = (const float2*)W;
  for (int i = t; i < 256 * HP; i += 256) {
    float2 w = W2[i];
    Wl[i] = pack2(w.x, w.y);
  }
  __syncthreads();

  int wid = blockIdx.x * 4 + (t >> 6);
  int nw  = gridDim.x * 4;
  int jp  = t & 63;
  for (int n = wid; n < N; n += nw) {
    const float4* hn = (const float4*)(h + (size_t)n * HH);
    float a0 = 0.f, a1 = 0.f, b0 = 0.f, b1 = 0.f;
    #pragma unroll 8
    for (int k4 = 0; k4 < 32; ++k4) {
      float4 hv = hn[k4];
      float xs[4] = {hv.x, hv.y, hv.z, hv.w};
      #pragma unroll
      for (int u = 0; u < 4; ++u) {
        int k = 4 * k4 + u;
        unsigned wa = Wl[k * HP + jp];
        unsigned wb = Wl[(128 + k) * HP + jp];
        a0 += xs[u] * blo(wa); a1 += xs[u] * bhi(wa);
        b0 += xs[u] * blo(wb); b1 += xs[u] * bhi(wb);
      }
    }
    a0 += bias[2 * jp]; a1 += bias[2 * jp + 1];
    Aout[(size_t)n * HP + jp] = pack2(a0, a1);
    Bout[(size_t)n * HP + jp] = pack2(b0, b1);
  }
}

// ---------- MFMA edge kernels, wave-private 16-edge tiles, NO inner barriers ----------
// Gathers are COALESCED per-row (lane=feature-pair), summed, bounced through LDS into
// the C-layout the tail-MFMA epilogue needs. Layer-1 tail via operand-swapped MFMA;
// layer-2 MFMA; run-combined atomic scatter (dst-sorted).
template<int MODE>
__global__ __launch_bounds__(512, 4) void edge_kernel(
    const unsigned* __restrict__ Apart, const unsigned* __restrict__ Bpart,
    const float* __restrict__ W1,       // (276,128); rows 256..275 = tail
    const float* __restrict__ W2, const float* __restrict__ b2,
    const float* __restrict__ Wv, const float* __restrict__ ba_p,
    const int* __restrict__ src, const int* __restrict__ dst,
    const int* __restrict__ perm,
    const float* __restrict__ coords, const float* __restrict__ afeat,
    float* __restrict__ out_agg, int E)
{
  __shared__ __align__(16) unsigned short W2Ts[128 * 136]; // 34.8 KB, n-major bf16
  __shared__ __align__(16) unsigned mhl[8][16 * 68];       // 34.8 KB wave-private (bounce + mh)

  const int t = threadIdx.x;
  const int lane = t & 63;
  const int w = t >> 6;                       // 0..7
  const int col = lane & 15;
  const int quad = lane >> 4;

  // stage W2 transposed as bf16 (once per block)
  for (int i = t; i < 128 * 128; i += 512) {
    int k = i >> 7, n = i & 127;
    W2Ts[n * 136 + k] = f2b(W2[i]);
  }

  // tail-weight A-fragments in registers (k-permutation: k<16 -> a_k row 260+k;
  // k 16..19 -> rad,|dx|,|dy|,|dz| rows 256..259; k>=20 -> 0)
  unsigned WtA[8][4];
  #pragma unroll
  for (int nt = 0; nt < 8; ++nt) {
    #pragma unroll
    for (int jp = 0; jp < 4; ++jp) {
      int k0 = 8 * quad + 2 * jp, k1 = k0 + 1;
      int n = nt * 16 + col;
      float w0 = (k0 < 16) ? W1[(260 + k0) * 128 + n] : (k0 < 20 ? W1[(240 + k0) * 128 + n] : 0.f);
      float w1 = (k1 < 16) ? W1[(260 + k1) * 128 + n] : (k1 < 20 ? W1[(240 + k1) * 128 + n] : 0.f);
      WtA[nt][jp] = pack2(w0, w1);
    }
  }
  float b2reg[8], wvreg[8];
  #pragma unroll
  for (int nt = 0; nt < 8; ++nt) {
    int n = nt * 16 + col;
    b2reg[nt] = b2[n];
    wvreg[nt] = Wv[n];
  }
  const float bav = (MODE == 0) ? ba_p[0] : 0.f;
  __syncthreads();                            // W2Ts ready (only block-wide barrier)

  const int ntiles = (E + 15) >> 4;
  const int nwaves = gridDim.x * 8;
  for (int tile = blockIdx.x * 8 + w; tile < ntiles; tile += nwaves) {
    const int e0 = tile * 16;

    // ---- per-edge scalars in lanes 0..15, broadcast via shuffles ----
    int pe0 = 0, s0 = 0, d0 = 0;
    float dx0 = 0.f, dy0 = 0.f, dz0 = 0.f, rad0 = 0.f;
    if (lane < 16) {
      int eg = e0 + lane;
      bool v = eg < E;
      pe0 = v ? perm[eg] : 0;
      s0 = v ? src[pe0] : 0;
      d0 = v ? dst[pe0] : 0;
      dx0 = coords[s0*3+0] - coords[d0*3+0];
      dy0 = coords[s0*3+1] - coords[d0*3+1];
      dz0 = coords[s0*3+2] - coords[d0*3+2];
      rad0 = sqrtf(dx0*dx0 + dy0*dy0 + dz0*dz0);
    }
    const int pe = __shfl(pe0, col, 64);
    const float dvx = __shfl(dx0, col, 64);
    const float dvy = __shfl(dy0, col, 64);
    const float dvz = __shfl(dz0, col, 64);
    const float dvr = __shfl(rad0, col, 64);

    // ---- COALESCED gathers: lane = feature-pair, one 256B row per edge per matrix ----
    unsigned wa[16], wb[16];
    #pragma unroll
    for (int i = 0; i < 16; ++i) {
      int sAi = __shfl(s0, i, 64);
      int dBi = __shfl(d0, i, 64);
      wa[i] = Apart[(size_t)sAi * HP + lane];
      wb[i] = Bpart[(size_t)dBi * HP + lane];
    }
    // sum partials, bounce into mhl in [edge][feature-pair] layout
    #pragma unroll
    for (int i = 0; i < 16; ++i) {
      float f0 = blo(wa[i]) + blo(wb[i]);
      float f1 = bhi(wa[i]) + bhi(wb[i]);
      mhl[w][i * 68 + lane] = pack2(f0, f1);
    }

    // ---- tail B-fragment: B[k=8*quad+j][n=edge col] ----
    unsigned tb0, tb1, tb2, tb3;
    if (quad < 2) {
      const float4* ap = (const float4*)(afeat + (size_t)pe * 16 + quad * 8);
      float4 a0 = ap[0], a1 = ap[1];
      tb0 = pack2(a0.x, a0.y); tb1 = pack2(a0.z, a0.w);
      tb2 = pack2(a1.x, a1.y); tb3 = pack2(a1.z, a1.w);
    } else if (quad == 2) {
      tb0 = pack2(dvr, fabsf(dvx)); tb1 = pack2(fabsf(dvy), fabsf(dvz));
      tb2 = 0u; tb3 = 0u;
    } else {
      tb0 = 0u; tb1 = 0u; tb2 = 0u; tb3 = 0u;
    }
    uint4v tbv = {tb0, tb1, tb2, tb3};
    short8 tailB = __builtin_bit_cast(short8, tbv);

    // ---- tail MFMAs + bounced partials + silu -> mhl (A-layout for layer 2) ----
    // Each lane reads then overwrites the SAME address (wave-in-order DS => safe).
    #pragma unroll
    for (int nt = 0; nt < 8; ++nt) {
      uint2 ga = *(const uint2*)&mhl[w][col * 68 + 8 * nt + 2 * quad];
      float4v zero = {0.f, 0.f, 0.f, 0.f};
      float4v l1 = __builtin_amdgcn_mfma_f32_16x16x32_bf16(
          __builtin_bit_cast(short8, *(const uint4v*)WtA[nt]), tailB, zero, 0, 0, 0);
      float v0 = silu_f(l1[0] + blo(ga.x));
      float v1 = silu_f(l1[1] + bhi(ga.x));
      float v2 = silu_f(l1[2] + blo(ga.y));
      float v3 = silu_f(l1[3] + bhi(ga.y));
      uint2 pk = make_uint2(pack2(v0, v1), pack2(v2, v3));
      *(uint2*)&mhl[w][col * 68 + 8 * nt + 2 * quad] = pk;
    }

    // ---- layer 2 via MFMA (wave covers 16 edges x 128 outputs) ----
    float4v acc[8] = {{0,0,0,0},{0,0,0,0},{0,0,0,0},{0,0,0,0},
                      {0,0,0,0},{0,0,0,0},{0,0,0,0},{0,0,0,0}};
    #pragma unroll
    for (int ks = 0; ks < 4; ++ks) {
      short8 af = __builtin_bit_cast(short8,
          *(const uint4v*)&mhl[w][col * 68 + ks * 16 + 4 * quad]);
      #pragma unroll
      for (int nt = 0; nt < 8; ++nt) {
        const unsigned short* bp = &W2Ts[(nt*16 + col)*136 + ks*32 + quad*8];
        short8 bf = __builtin_bit_cast(short8, *(const uint4v*)bp);
        acc[nt] = __builtin_amdgcn_mfma_f32_16x16x32_bf16(af, bf, acc[nt], 0, 0, 0);
      }
    }

    // ---- epilogue: bias+silu, head dot, 16-lane reduce, run-combined scatter ----
    float vv[8][4];
    float p[4] = {0.f, 0.f, 0.f, 0.f};
    #pragma unroll
    for (int nt = 0; nt < 8; ++nt)
      #pragma unroll
      for (int r = 0; r < 4; ++r) {
        float v = silu_f(acc[nt][r] + b2reg[nt]);
        vv[nt][r] = v;
        p[r] += v * wvreg[nt];
      }
    #pragma unroll
    for (int r = 0; r < 4; ++r) {
      #pragma unroll
      for (int off = 1; off < 16; off <<= 1) p[r] += __shfl_xor(p[r], off, 64);
    }
    int dq[4];
    #pragma unroll
    for (int r = 0; r < 4; ++r) dq[r] = __shfl(d0, quad * 4 + r, 64);

    if (MODE == 0) {
      float att[4];
      #pragma unroll
      for (int r = 0; r < 4; ++r) {
        int eg = e0 + quad * 4 + r;
        att[r] = (eg < E) ? 1.f / (1.f + __expf(-(p[r] + bav))) : 0.f;
      }
      #pragma unroll
      for (int nt = 0; nt < 8; ++nt) {
        int n = nt * 16 + col;
        float accm = att[0] * vv[nt][0];
        int dprev = dq[0];
        #pragma unroll
        for (int r = 1; r < 4; ++r) {
          float val = att[r] * vv[nt][r];
          if (dq[r] == dprev) accm += val;     // quad-uniform branch
          else {
            unsafeAtomicAdd(&out_agg[(size_t)dprev * HH + n], accm);
            dprev = dq[r]; accm = val;
          }
        }
        unsafeAtomicAdd(&out_agg[(size_t)dprev * HH + n], accm);
      }
    } else {
      float dxq[4], dyq[4], dzq[4], rq[4];
      #pragma unroll
      for (int r = 0; r < 4; ++r) {
        dxq[r] = __shfl(dx0, quad * 4 + r, 64);
        dyq[r] = __shfl(dy0, quad * 4 + r, 64);
        dzq[r] = __shfl(dz0, quad * 4 + r, 64);
        rq[r]  = __shfl(rad0, quad * 4 + r, 64);
      }
      if (col < 3) {
        float accm = 0.f;
        int dprev = dq[0];
        #pragma unroll
        for (int r = 0; r < 4; ++r) {
          int eg = e0 + quad * 4 + r;
          float fac = (eg < E) ? p[r] / (rq[r] + 1.f) : 0.f;
          float dcomp = (col == 0) ? dxq[r] : ((col == 1) ? dyq[r] : dzq[r]);
          float val = fac * dcomp;
          if (r > 0 && dq[r] != dprev) {
            unsafeAtomicAdd(&out_agg[(size_t)dprev * 3 + col], accm);
            dprev = dq[r]; accm = 0.f;
          }
          accm += val;
        }
        unsafeAtomicAdd(&out_agg[(size_t)dprev * 3 + col], accm);
      }
    }
    // no barrier: wave-private LDS + in-order DS ops make next tile safe
  }
}

// ---------- node MLP layer 1 ----------
__global__ __launch_bounds__(256) void node_l1_kernel(
    const float* __restrict__ h, const float* __restrict__ h_agg,
    const float* __restrict__ Wn1, const float* __restrict__ bn1,
    unsigned* __restrict__ g, int N)
{
  __shared__ unsigned Wl[256 * HP];
  int t = threadIdx.x;
  const float2* W2 = (const float2*)Wn1;
  for (int i = t; i < 256 * HP; i += 256) { float2 w = W2[i]; Wl[i] = pack2(w.x, w.y); }
  __syncthreads();

  int wid = blockIdx.x * 4 + (t >> 6);
  int nw  = gridDim.x * 4;
  int jp  = t & 63;
  for (int n = wid; n < N; n += nw) {
    float a0 = bn1[2*jp], a1 = bn1[2*jp + 1];
    const float4* hn = (const float4*)(h + (size_t)n * HH);
    const float4* gn = (const float4*)(h_agg + (size_t)n * HH);
    #pragma unroll 4
    for (int k4 = 0; k4 < 32; ++k4) {
      float4 hv = hn[k4];
      float xs[4] = {hv.x, hv.y, hv.z, hv.w};
      #pragma unroll
      for (int u = 0; u < 4; ++u) {
        unsigned w = Wl[(4*k4 + u) * HP + jp];
        a0 += xs[u] * blo(w); a1 += xs[u] * bhi(w);
      }
    }
    #pragma unroll 4
    for (int k4 = 0; k4 < 32; ++k4) {
      float4 hv = gn[k4];
      float xs[4] = {hv.x, hv.y, hv.z, hv.w};
      #pragma unroll
      for (int u = 0; u < 4; ++u) {
        unsigned w = Wl[(128 + 4*k4 + u) * HP + jp];
        a0 += xs[u] * blo(w); a1 += xs[u] * bhi(w);
      }
    }
    g[(size_t)n * HP + jp] = pack2(silu_f(a0), silu_f(a1));
  }
}

// ---------- node MLP layer 2 ----------
__global__ __launch_bounds__(256) void node_l2_kernel(
    const unsigned* __restrict__ g, const float* __restrict__ h,
    const float* __restrict__ Wn2, const float* __restrict__ bn2,
    float* __restrict__ hout, int N)
{
  __shared__ unsigned Wl[128 * HP];
  int t = threadIdx.x;
  const float2* W2 = (const float2*)Wn2;
  for (int i = t; i < 128 * HP; i += 256) { float2 w = W2[i]; Wl[i] = pack2(w.x, w.y); }
  __syncthreads();

  int wid = blockIdx.x * 4 + (t >> 6);
  int nw  = gridDim.x * 4;
  int jp  = t & 63;
  for (int n = wid; n < N; n += nw) {
    float a0 = bn2[2*jp], a1 = bn2[2*jp + 1];
    const uint2* gn = (const uint2*)(g + (size_t)n * HP);
    #pragma unroll 4
    for (int k2 = 0; k2 < 32; ++k2) {
      uint2 gp = gn[k2];
      float x0 = blo(gp.x), x1 = bhi(gp.x), x2 = blo(gp.y), x3 = bhi(gp.y);
      unsigned w0 = Wl[(4*k2    ) * HP + jp];
      unsigned w1 = Wl[(4*k2 + 1) * HP + jp];
      unsigned w2 = Wl[(4*k2 + 2) * HP + jp];
      unsigned w3 = Wl[(4*k2 + 3) * HP + jp];
      a0 += x0*blo(w0) + x1*blo(w1) + x2*blo(w2) + x3*blo(w3);
      a1 += x0*bhi(w0) + x1*bhi(w1) + x2*bhi(w2) + x3*bhi(w3);
    }
    float2 hv = ((const float2*)h)[(size_t)n * HP + jp];
    ((float2*)hout)[(size_t)n * HP + jp] = make_float2(hv.x + a0, hv.y + a1);
  }
}

// ---------- coords_out = coords + x_agg ----------
__global__ void coords_out_kernel(const float* __restrict__ coords,
                                  const float* __restrict__ x_agg,
                                  float* __restrict__ out, int n3)
{
  int i = blockIdx.x * blockDim.x + threadIdx.x;
  if (i < n3) out[i] = coords[i] + x_agg[i];
}

extern "C" void kernel_launch(void* const* d_in, const int* in_sizes, int n_in,
                              void* d_out, int out_size, void* d_ws, size_t ws_size,
                              hipStream_t stream)
{
  const float* h      = (const float*)d_in[0];
  const float* coords = (const float*)d_in[1];
  const float* afeat  = (const float*)d_in[2];
  const int*   src    = (const int*)d_in[3];
  const int*   dst    = (const int*)d_in[4];
  const float* We1 = (const float*)d_in[5];
  const float* be1 = (const float*)d_in[6];
  const float* We2 = (const float*)d_in[7];
  const float* be2 = (const float*)d_in[8];
  const float* Wa  = (const float*)d_in[9];
  const float* ba  = (const float*)d_in[10];
  const float* Wn1 = (const float*)d_in[11];
  const float* bn1 = (const float*)d_in[12];
  const float* Wn2 = (const float*)d_in[13];
  const float* bn2 = (const float*)d_in[14];
  const float* Wc1 = (const float*)d_in[15];
  const float* bc1 = (const float*)d_in[16];
  const float* Wc2 = (const float*)d_in[17];
  const float* bc2 = (const float*)d_in[18];
  const float* Wc3 = (const float*)d_in[19];

  const int E = in_sizes[3];
  const int N = in_sizes[0] / HH;

  unsigned* A1 = (unsigned*)d_ws;
  unsigned* B1 = A1 + (size_t)N * HP;
  unsigned* Ac = B1 + (size_t)N * HP;
  unsigned* Bc = Ac + (size_t)N * HP;
  float* h_agg = (float*)(Bc + (size_t)N * HP);
  float* x_agg = h_agg + (size_t)N * HH;
  int*   perm  = (int*)(x_agg + (size_t)N * 3);
  unsigned* histb = (unsigned*)(perm + E);
  unsigned* offs  = histb + N;
  unsigned* bsums = offs + N;
  unsigned* gbuf = A1;                        // reuse after edge kernels finish

  hipMemsetAsync(histb, 0, (size_t)N * sizeof(unsigned), stream);
  hipMemsetAsync(h_agg, 0, ((size_t)N * HH + (size_t)N * 3) * sizeof(float), stream);

  // counting sort of edges by dst
  hist_kernel<<<512, 256, 0, stream>>>(dst, histb, E);
  int NB = (N + 255) / 256;
  scan_block_kernel<<<NB, 256, 0, stream>>>(histb, offs, bsums, N);
  scan_top_kernel<<<1, 256, 0, stream>>>(bsums, NB);
  scan_add_kernel<<<NB, 256, 0, stream>>>(offs, bsums, N);
  scatter_kernel<<<512, 256, 0, stream>>>(dst, offs, perm, E);

  precompute_kernel<<<512, 256, 0, stream>>>(h, We1, be1, A1, B1, N);
  precompute_kernel<<<512, 256, 0, stream>>>(h, Wc1, bc1, Ac, Bc, N);

  edge_kernel<0><<<512, 512, 0, stream>>>(A1, B1, We1, We2, be2, Wa, ba,
                                          src, dst, perm, coords, afeat, h_agg, E);
  edge_kernel<1><<<512, 512, 0, stream>>>(Ac, Bc, Wc1, Wc2, bc2, Wc3, nullptr,
                                          src, dst, perm, coords, afeat, x_agg, E);

  node_l1_kernel<<<512, 256, 0, stream>>>(h, h_agg, Wn1, bn1, gbuf, N);
  node_l2_kernel<<<1024, 256, 0, stream>>>(gbuf, h, Wn2, bn2, (float*)d_out, N);
  coords_out_kernel<<<(N * 3 + 255) / 256, 256, 0, stream>>>(
      coords, x_agg, (float*)d_out + (size_t)N * HH, N * 3);
}

// Round 6
// 1376.117 us; speedup vs baseline: 1.1143x; 1.0144x over previous
//
#include <hip/hip_runtime.h>
#include <math.h>

#define HH 128
#define HP 64   // u32 pairs per 128-feature row

typedef __attribute__((ext_vector_type(8))) short short8;
typedef __attribute__((ext_vector_type(4))) float float4v;
typedef __attribute__((ext_vector_type(4))) unsigned uint4v;

// ---------- helpers ----------
__device__ __forceinline__ float blo(unsigned w){ return __uint_as_float(w << 16); }
__device__ __forceinline__ float bhi(unsigned w){ return __uint_as_float(w & 0xffff0000u); }
__device__ __forceinline__ unsigned short f2b(float x){
  unsigned u = __float_as_uint(x);
  u += 0x7fffu + ((u >> 16) & 1u);           // RNE to bf16
  return (unsigned short)(u >> 16);
}
__device__ __forceinline__ unsigned pack2(float a, float b){
  return (unsigned)f2b(a) | ((unsigned)f2b(b) << 16);
}
__device__ __forceinline__ float silu_f(float x){ return x / (1.f + __expf(-x)); }

// ---------- sort-by-dst kernels ----------
__global__ void hist_kernel(const int* __restrict__ dst, unsigned* __restrict__ hist, int E){
  int i = blockIdx.x * blockDim.x + threadIdx.x;
  int st = gridDim.x * blockDim.x;
  for (; i < E; i += st) atomicAdd(&hist[dst[i]], 1u);
}

__global__ void scan_block_kernel(const unsigned* __restrict__ hist,
                                  unsigned* __restrict__ offs,
                                  unsigned* __restrict__ bsums, int N){
  __shared__ unsigned s[256];
  int t = threadIdx.x, g = blockIdx.x * 256 + t;
  unsigned v = (g < N) ? hist[g] : 0u;
  s[t] = v; __syncthreads();
  for (int o = 1; o < 256; o <<= 1) {
    unsigned a = (t >= o) ? s[t - o] : 0u; __syncthreads();
    s[t] += a; __syncthreads();
  }
  unsigned incl = s[t];
  if (g < N) offs[g] = incl - v;
  if (t == 255) bsums[blockIdx.x] = incl;
}

__global__ void scan_top_kernel(unsigned* __restrict__ bsums, int NB){
  __shared__ unsigned s[256];
  int t = threadIdx.x;
  unsigned v = (t < NB) ? bsums[t] : 0u;
  s[t] = v; __syncthreads();
  for (int o = 1; o < 256; o <<= 1) {
    unsigned a = (t >= o) ? s[t - o] : 0u; __syncthreads();
    s[t] += a; __syncthreads();
  }
  unsigned incl = s[t];
  if (t < NB) bsums[t] = incl - v;           // exclusive
}

__global__ void scan_add_kernel(unsigned* __restrict__ offs,
                                const unsigned* __restrict__ bsums, int N){
  int g = blockIdx.x * 256 + threadIdx.x;
  if (g < N) offs[g] += bsums[blockIdx.x];
}

// ---------- prep: sequential reads of src/dst/afeat/coords, write 64B record to sorted slot ----------
// record layout (16 u32): w0..w9 = tail bf16 pairs (a0..a15, rad,|dx|, |dy|,|dz|),
//                         w10 = src, w11 = dst, w12..15 = dx,dy,dz,rad (f32)
__global__ void scatter_prep_kernel(const int* __restrict__ src, const int* __restrict__ dst,
                                    const float* __restrict__ coords,
                                    const float* __restrict__ afeat,
                                    unsigned* __restrict__ offs,
                                    unsigned* __restrict__ rec, int E){
  int i = blockIdx.x * blockDim.x + threadIdx.x;
  int st = gridDim.x * blockDim.x;
  for (; i < E; i += st) {
    int s = src[i], d = dst[i];
    unsigned pos = atomicAdd(&offs[d], 1u);
    float dx = coords[s*3+0] - coords[d*3+0];
    float dy = coords[s*3+1] - coords[d*3+1];
    float dz = coords[s*3+2] - coords[d*3+2];
    float rad = sqrtf(dx*dx + dy*dy + dz*dz);
    const float4* ap = (const float4*)(afeat + (size_t)i * 16);
    float4 a0 = ap[0], a1 = ap[1], a2 = ap[2], a3 = ap[3];
    unsigned* r = rec + (size_t)pos * 16;
    uint4v w0 = {pack2(a0.x,a0.y), pack2(a0.z,a0.w), pack2(a1.x,a1.y), pack2(a1.z,a1.w)};
    uint4v w1 = {pack2(a2.x,a2.y), pack2(a2.z,a2.w), pack2(a3.x,a3.y), pack2(a3.z,a3.w)};
    uint4v w2 = {pack2(rad,fabsf(dx)), pack2(fabsf(dy),fabsf(dz)), (unsigned)s, (unsigned)d};
    uint4v w3 = {__float_as_uint(dx), __float_as_uint(dy), __float_as_uint(dz), __float_as_uint(rad)};
    *(uint4v*)(r + 0)  = w0;
    *(uint4v*)(r + 4)  = w1;
    *(uint4v*)(r + 8)  = w2;
    *(uint4v*)(r + 12) = w3;
  }
}

// ---------- per-node precompute: A = h@W[0:128] + bias, B = h@W[128:256] ----------
__global__ __launch_bounds__(256) void precompute_kernel(
    const float* __restrict__ h, const float* __restrict__ W,
    const float* __restrict__ bias,
    unsigned* __restrict__ Aout, unsigned* __restrict__ Bout, int N)
{
  __shared__ unsigned Wl[256 * HP];           // 64 KB
  int t = threadIdx.x;
  const float2* W2 = (const float2*)W;
  for (int i = t; i < 256 * HP; i += 256) {
    float2 w = W2[i];
    Wl[i] = pack2(w.x, w.y);
  }
  __syncthreads();

  int wid = blockIdx.x * 4 + (t >> 6);
  int nw  = gridDim.x * 4;
  int jp  = t & 63;
  for (int n = wid; n < N; n += nw) {
    const float4* hn = (const float4*)(h + (size_t)n * HH);
    float a0 = 0.f, a1 = 0.f, b0 = 0.f, b1 = 0.f;
    #pragma unroll 8
    for (int k4 = 0; k4 < 32; ++k4) {
      float4 hv = hn[k4];
      float xs[4] = {hv.x, hv.y, hv.z, hv.w};
      #pragma unroll
      for (int u = 0; u < 4; ++u) {
        int k = 4 * k4 + u;
        unsigned wa = Wl[k * HP + jp];
        unsigned wb = Wl[(128 + k) * HP + jp];
        a0 += xs[u] * blo(wa); a1 += xs[u] * bhi(wa);
        b0 += xs[u] * blo(wb); b1 += xs[u] * bhi(wb);
      }
    }
    a0 += bias[2 * jp]; a1 += bias[2 * jp + 1];
    Aout[(size_t)n * HP + jp] = pack2(a0, a1);
    Bout[(size_t)n * HP + jp] = pack2(b0, b1);
  }
}

// ---------- MFMA edge kernels, wave-private 16-edge tiles, NO inner barriers ----------
// Front-end: one coalesced uint4/lane record read per tile; fields via shuffles.
// Gathers coalesced per-row; bounce through LDS into C-layout; tail via swapped-operand
// MFMA; layer-2 MFMA; run-combined atomic scatter (dst-sorted).
template<int MODE>
__global__ __launch_bounds__(512, 4) void edge_kernel(
    const unsigned* __restrict__ Apart, const unsigned* __restrict__ Bpart,
    const float* __restrict__ W1,       // (276,128); rows 256..275 = tail
    const float* __restrict__ W2, const float* __restrict__ b2,
    const float* __restrict__ Wv, const float* __restrict__ ba_p,
    const unsigned* __restrict__ rec,
    float* __restrict__ out_agg, int E)
{
  __shared__ __align__(16) unsigned short W2Ts[128 * 136]; // 34.8 KB, n-major bf16
  __shared__ __align__(16) unsigned mhl[8][16 * 68];       // 34.8 KB wave-private

  const int t = threadIdx.x;
  const int lane = t & 63;
  const int w = t >> 6;                       // 0..7
  const int col = lane & 15;
  const int quad = lane >> 4;

  // stage W2 transposed as bf16 (once per block)
  for (int i = t; i < 128 * 128; i += 512) {
    int k = i >> 7, n = i & 127;
    W2Ts[n * 136 + k] = f2b(W2[i]);
  }

  // tail-weight A-fragments (k<16 -> a_k row 260+k; k16..19 -> rad,|dx|,|dy|,|dz| rows 256..259)
  unsigned WtA[8][4];
  #pragma unroll
  for (int nt = 0; nt < 8; ++nt) {
    #pragma unroll
    for (int jp = 0; jp < 4; ++jp) {
      int k0 = 8 * quad + 2 * jp, k1 = k0 + 1;
      int n = nt * 16 + col;
      float w0 = (k0 < 16) ? W1[(260 + k0) * 128 + n] : (k0 < 20 ? W1[(240 + k0) * 128 + n] : 0.f);
      float w1 = (k1 < 16) ? W1[(260 + k1) * 128 + n] : (k1 < 20 ? W1[(240 + k1) * 128 + n] : 0.f);
      WtA[nt][jp] = pack2(w0, w1);
    }
  }
  float b2reg[8], wvreg[8];
  #pragma unroll
  for (int nt = 0; nt < 8; ++nt) {
    int n = nt * 16 + col;
    b2reg[nt] = b2[n];
    wvreg[nt] = Wv[n];
  }
  const float bav = (MODE == 0) ? ba_p[0] : 0.f;
  __syncthreads();                            // W2Ts ready (only block-wide barrier)

  const int ntiles = (E + 15) >> 4;
  const int nwaves = gridDim.x * 8;
  for (int tile = blockIdx.x * 8 + w; tile < ntiles; tile += nwaves) {
    const int e0 = tile * 16;

    // ---- coalesced record read: 16 edges x 16 u32 = 64 uint4, one per lane ----
    uint4v rv = *(const uint4v*)(rec + (size_t)tile * 256 + lane * 4);

    // ---- COALESCED gathers: lane = feature-pair; indices via shuffles ----
    unsigned wa[16], wb[16];
    #pragma unroll
    for (int i = 0; i < 16; ++i) {
      int sAi = __shfl((int)rv.z, 4 * i + 2, 64);
      int dBi = __shfl((int)rv.w, 4 * i + 2, 64);
      wa[i] = Apart[(size_t)sAi * HP + lane];
      wb[i] = Bpart[(size_t)dBi * HP + lane];
    }
    // sum partials, bounce into mhl in [edge][feature-pair] layout
    #pragma unroll
    for (int i = 0; i < 16; ++i) {
      float f0 = blo(wa[i]) + blo(wb[i]);
      float f1 = bhi(wa[i]) + bhi(wb[i]);
      mhl[w][i * 68 + lane] = pack2(f0, f1);
    }

    // ---- tail B-fragment: B[k=8*quad+j][n=edge col] from record shuffles ----
    {
      int sl = 4 * col + quad;
      unsigned tb0 = (unsigned)__shfl((int)rv.x, sl, 64);
      unsigned tb1 = (unsigned)__shfl((int)rv.y, sl, 64);
      unsigned tb2 = (unsigned)__shfl((int)rv.z, sl, 64);
      unsigned tb3 = (unsigned)__shfl((int)rv.w, sl, 64);
      if (quad >= 2) { tb2 = 0u; tb3 = 0u; }
      if (quad == 3) { tb0 = 0u; tb1 = 0u; }
      uint4v tbv = {tb0, tb1, tb2, tb3};
      short8 tailB = __builtin_bit_cast(short8, tbv);

      // ---- tail MFMAs + bounced partials + silu -> mhl (A-layout for layer 2) ----
      #pragma unroll
      for (int nt = 0; nt < 8; ++nt) {
        uint2 ga = *(const uint2*)&mhl[w][col * 68 + 8 * nt + 2 * quad];
        float4v zero = {0.f, 0.f, 0.f, 0.f};
        float4v l1 = __builtin_amdgcn_mfma_f32_16x16x32_bf16(
            __builtin_bit_cast(short8, *(const uint4v*)WtA[nt]), tailB, zero, 0, 0, 0);
        float v0 = silu_f(l1[0] + blo(ga.x));
        float v1 = silu_f(l1[1] + bhi(ga.x));
        float v2 = silu_f(l1[2] + blo(ga.y));
        float v3 = silu_f(l1[3] + bhi(ga.y));
        uint2 pk = make_uint2(pack2(v0, v1), pack2(v2, v3));
        *(uint2*)&mhl[w][col * 68 + 8 * nt + 2 * quad] = pk;
      }
    }

    // ---- layer 2 via MFMA (wave covers 16 edges x 128 outputs) ----
    float4v acc[8] = {{0,0,0,0},{0,0,0,0},{0,0,0,0},{0,0,0,0},
                      {0,0,0,0},{0,0,0,0},{0,0,0,0},{0,0,0,0}};
    #pragma unroll
    for (int ks = 0; ks < 4; ++ks) {
      short8 af = __builtin_bit_cast(short8,
          *(const uint4v*)&mhl[w][col * 68 + ks * 16 + 4 * quad]);
      #pragma unroll
      for (int nt = 0; nt < 8; ++nt) {
        const unsigned short* bp = &W2Ts[(nt*16 + col)*136 + ks*32 + quad*8];
        short8 bf = __builtin_bit_cast(short8, *(const uint4v*)bp);
        acc[nt] = __builtin_amdgcn_mfma_f32_16x16x32_bf16(af, bf, acc[nt], 0, 0, 0);
      }
    }

    // ---- epilogue: bias+silu, head dot, 16-lane reduce, run-combined scatter ----
    float vv[8][4];
    float p[4] = {0.f, 0.f, 0.f, 0.f};
    #pragma unroll
    for (int nt = 0; nt < 8; ++nt)
      #pragma unroll
      for (int r = 0; r < 4; ++r) {
        float v = silu_f(acc[nt][r] + b2reg[nt]);
        vv[nt][r] = v;
        p[r] += v * wvreg[nt];
      }
    #pragma unroll
    for (int r = 0; r < 4; ++r) {
      #pragma unroll
      for (int off = 1; off < 16; off <<= 1) p[r] += __shfl_xor(p[r], off, 64);
    }
    int dq[4];
    #pragma unroll
    for (int r = 0; r < 4; ++r) dq[r] = __shfl((int)rv.w, 4 * (quad * 4 + r) + 2, 64);

    if (MODE == 0) {
      float att[4];
      #pragma unroll
      for (int r = 0; r < 4; ++r) {
        int eg = e0 + quad * 4 + r;
        att[r] = (eg < E) ? 1.f / (1.f + __expf(-(p[r] + bav))) : 0.f;
      }
      #pragma unroll
      for (int nt = 0; nt < 8; ++nt) {
        int n = nt * 16 + col;
        float accm = att[0] * vv[nt][0];
        int dprev = dq[0];
        #pragma unroll
        for (int r = 1; r < 4; ++r) {
          float val = att[r] * vv[nt][r];
          if (dq[r] == dprev) accm += val;     // quad-uniform branch
          else {
            unsafeAtomicAdd(&out_agg[(size_t)dprev * HH + n], accm);
            dprev = dq[r]; accm = val;
          }
        }
        unsafeAtomicAdd(&out_agg[(size_t)dprev * HH + n], accm);
      }
    } else {
      float dxq[4], dyq[4], dzq[4], rq[4];
      #pragma unroll
      for (int r = 0; r < 4; ++r) {
        int sl = 4 * (quad * 4 + r) + 3;
        dxq[r] = __uint_as_float((unsigned)__shfl((int)rv.x, sl, 64));
        dyq[r] = __uint_as_float((unsigned)__shfl((int)rv.y, sl, 64));
        dzq[r] = __uint_as_float((unsigned)__shfl((int)rv.z, sl, 64));
        rq[r]  = __uint_as_float((unsigned)__shfl((int)rv.w, sl, 64));
      }
      if (col < 3) {
        float accm = 0.f;
        int dprev = dq[0];
        #pragma unroll
        for (int r = 0; r < 4; ++r) {
          int eg = e0 + quad * 4 + r;
          float fac = (eg < E) ? p[r] / (rq[r] + 1.f) : 0.f;
          float dcomp = (col == 0) ? dxq[r] : ((col == 1) ? dyq[r] : dzq[r]);
          float val = fac * dcomp;
          if (r > 0 && dq[r] != dprev) {
            unsafeAtomicAdd(&out_agg[(size_t)dprev * 3 + col], accm);
            dprev = dq[r]; accm = 0.f;
          }
          accm += val;
        }
        unsafeAtomicAdd(&out_agg[(size_t)dprev * 3 + col], accm);
      }
    }
    // no barrier: wave-private LDS + in-order DS ops make next tile safe
  }
}

// ---------- node MLP layer 1 ----------
__global__ __launch_bounds__(256) void node_l1_kernel(
    const float* __restrict__ h, const float* __restrict__ h_agg,
    const float* __restrict__ Wn1, const float* __restrict__ bn1,
    unsigned* __restrict__ g, int N)
{
  __shared__ unsigned Wl[256 * HP];
  int t = threadIdx.x;
  const float2* W2 = (const float2*)Wn1;
  for (int i = t; i < 256 * HP; i += 256) { float2 w = W2[i]; Wl[i] = pack2(w.x, w.y); }
  __syncthreads();

  int wid = blockIdx.x * 4 + (t >> 6);
  int nw  = gridDim.x * 4;
  int jp  = t & 63;
  for (int n = wid; n < N; n += nw) {
    float a0 = bn1[2*jp], a1 = bn1[2*jp + 1];
    const float4* hn = (const float4*)(h + (size_t)n * HH);
    const float4* gn = (const float4*)(h_agg + (size_t)n * HH);
    #pragma unroll 4
    for (int k4 = 0; k4 < 32; ++k4) {
      float4 hv = hn[k4];
      float xs[4] = {hv.x, hv.y, hv.z, hv.w};
      #pragma unroll
      for (int u = 0; u < 4; ++u) {
        unsigned w = Wl[(4*k4 + u) * HP + jp];
        a0 += xs[u] * blo(w); a1 += xs[u] * bhi(w);
      }
    }
    #pragma unroll 4
    for (int k4 = 0; k4 < 32; ++k4) {
      float4 hv = gn[k4];
      float xs[4] = {hv.x, hv.y, hv.z, hv.w};
      #pragma unroll
      for (int u = 0; u < 4; ++u) {
        unsigned w = Wl[(128 + 4*k4 + u) * HP + jp];
        a0 += xs[u] * blo(w); a1 += xs[u] * bhi(w);
      }
    }
    g[(size_t)n * HP + jp] = pack2(silu_f(a0), silu_f(a1));
  }
}

// ---------- node MLP layer 2 ----------
__global__ __launch_bounds__(256) void node_l2_kernel(
    const unsigned* __restrict__ g, const float* __restrict__ h,
    const float* __restrict__ Wn2, const float* __restrict__ bn2,
    float* __restrict__ hout, int N)
{
  __shared__ unsigned Wl[128 * HP];
  int t = threadIdx.x;
  const float2* W2 = (const float2*)Wn2;
  for (int i = t; i < 128 * HP; i += 256) { float2 w = W2[i]; Wl[i] = pack2(w.x, w.y); }
  __syncthreads();

  int wid = blockIdx.x * 4 + (t >> 6);
  int nw  = gridDim.x * 4;
  int jp  = t & 63;
  for (int n = wid; n < N; n += nw) {
    float a0 = bn2[2*jp], a1 = bn2[2*jp + 1];
    const uint2* gn = (const uint2*)(g + (size_t)n * HP);
    #pragma unroll 4
    for (int k2 = 0; k2 < 32; ++k2) {
      uint2 gp = gn[k2];
      float x0 = blo(gp.x), x1 = bhi(gp.x), x2 = blo(gp.y), x3 = bhi(gp.y);
      unsigned w0 = Wl[(4*k2    ) * HP + jp];
      unsigned w1 = Wl[(4*k2 + 1) * HP + jp];
      unsigned w2 = Wl[(4*k2 + 2) * HP + jp];
      unsigned w3 = Wl[(4*k2 + 3) * HP + jp];
      a0 += x0*blo(w0) + x1*blo(w1) + x2*blo(w2) + x3*blo(w3);
      a1 += x0*bhi(w0) + x1*bhi(w1) + x2*bhi(w2) + x3*bhi(w3);
    }
    float2 hv = ((const float2*)h)[(size_t)n * HP + jp];
    ((float2*)hout)[(size_t)n * HP + jp] = make_float2(hv.x + a0, hv.y + a1);
  }
}

// ---------- coords_out = coords + x_agg ----------
__global__ void coords_out_kernel(const float* __restrict__ coords,
                                  const float* __restrict__ x_agg,
                                  float* __restrict__ out, int n3)
{
  int i = blockIdx.x * blockDim.x + threadIdx.x;
  if (i < n3) out[i] = coords[i] + x_agg[i];
}

extern "C" void kernel_launch(void* const* d_in, const int* in_sizes, int n_in,
                              void* d_out, int out_size, void* d_ws, size_t ws_size,
                              hipStream_t stream)
{
  const float* h      = (const float*)d_in[0];
  const float* coords = (const float*)d_in[1];
  const float* afeat  = (const float*)d_in[2];
  const int*   src    = (const int*)d_in[3];
  const int*   dst    = (const int*)d_in[4];
  const float* We1 = (const float*)d_in[5];
  const float* be1 = (const float*)d_in[6];
  const float* We2 = (const float*)d_in[7];
  const float* be2 = (const float*)d_in[8];
  const float* Wa  = (const float*)d_in[9];
  const float* ba  = (const float*)d_in[10];
  const float* Wn1 = (const float*)d_in[11];
  const float* bn1 = (const float*)d_in[12];
  const float* Wn2 = (const float*)d_in[13];
  const float* bn2 = (const float*)d_in[14];
  const float* Wc1 = (const float*)d_in[15];
  const float* bc1 = (const float*)d_in[16];
  const float* Wc2 = (const float*)d_in[17];
  const float* bc2 = (const float*)d_in[18];
  const float* Wc3 = (const float*)d_in[19];

  const int E = in_sizes[3];
  const int N = in_sizes[0] / HH;
  const int Epad = (E + 15) & ~15;

  unsigned* A1 = (unsigned*)d_ws;
  unsigned* B1 = A1 + (size_t)N * HP;
  unsigned* Ac = B1 + (size_t)N * HP;
  unsigned* Bc = Ac + (size_t)N * HP;
  float* h_agg = (float*)(Bc + (size_t)N * HP);
  float* x_agg = h_agg + (size_t)N * HH;
  unsigned* rec   = (unsigned*)(x_agg + (size_t)N * 3);
  unsigned* histb = rec + (size_t)(Epad + 16) * 16;
  unsigned* offs  = histb + N;
  unsigned* bsums = offs + N;
  unsigned* gbuf = A1;                        // reuse after edge kernels finish

  hipMemsetAsync(histb, 0, (size_t)N * sizeof(unsigned), stream);
  hipMemsetAsync(h_agg, 0, ((size_t)N * HH + (size_t)N * 3) * sizeof(float), stream);
  // zero the record pad region (tiles may read past E)
  hipMemsetAsync(rec + (size_t)E * 16, 0, (size_t)(Epad + 16 - E) * 64, stream);

  // counting sort of edges by dst + record materialization
  hist_kernel<<<512, 256, 0, stream>>>(dst, histb, E);
  int NB = (N + 255) / 256;
  scan_block_kernel<<<NB, 256, 0, stream>>>(histb, offs, bsums, N);
  scan_top_kernel<<<1, 256, 0, stream>>>(bsums, NB);
  scan_add_kernel<<<NB, 256, 0, stream>>>(offs, bsums, N);
  scatter_prep_kernel<<<512, 256, 0, stream>>>(src, dst, coords, afeat, offs, rec, E);

  precompute_kernel<<<512, 256, 0, stream>>>(h, We1, be1, A1, B1, N);
  precompute_kernel<<<512, 256, 0, stream>>>(h, Wc1, bc1, Ac, Bc, N);

  edge_kernel<0><<<512, 512, 0, stream>>>(A1, B1, We1, We2, be2, Wa, ba,
                                          rec, h_agg, E);
  edge_kernel<1><<<512, 512, 0, stream>>>(Ac, Bc, Wc1, Wc2, bc2, Wc3, nullptr,
                                          rec, x_agg, E);

  node_l1_kernel<<<512, 256, 0, stream>>>(h, h_agg, Wn1, bn1, gbuf, N);
  node_l2_kernel<<<1024, 256, 0, stream>>>(gbuf, h, Wn2, bn2, (float*)d_out, N);
  coords_out_kernel<<<(N * 3 + 255) / 256, 256, 0, stream>>>(
      coords, x_agg, (float*)d_out + (size_t)N * HH, N * 3);
}